// Round 7
// baseline (2007.410 us; speedup 1.0000x reference)
//
#include <hip/hip_runtime.h>
#include <hip/hip_bf16.h>
#include <math.h>

// CVQNN classifier, N=64 modes, OUT=10, HBAR=2.
// Kernel 1 (1 block, 192 thr): build S (128x128 symplectic, 2 layers) and d.
//   Thread c holds column c of S in registers (ops are column-local).
//   Thread 128 carries the displacement vector d through the same ops.
//   Emits to ws: W[k][rr] = 2*S[rows[rr],k] (k<64, 1280 fl),
//                bias[rr] = d[rows[rr]] (20 fl), cterm[w] (10 fl).
// Kernel 2: W/bias/cterm in LDS (uniform-address broadcast reads).
//   Model (rounds 3/5/6): duration ~= per-CU LDS-pipe time; the LDS read
//   pipe saturates at ~8 resident waves/CU, so occupancy is NOT the lever
//   -- per-thread LDS volume is. Hence: TWO rows per thread sharing every
//   W read (320 b128/wave serves 128 rows, halving LDS volume), full
//   128B-line x bursts (compulsory-only FETCH + 16-deep MLP, round-4
//   lesson), and NO launch_bounds on this kernel: rounds 2/4/6 all spilled
//   by under-estimating live regs against a hard cap (the in-flight
//   ds_read dest regs are the unbudgeted ~20-30); round 1 proved this
//   2-row shape fits ~196 VGPR uncapped with NO spill, and low occupancy
//   is fine because the LDS pipe is the wall anyway.
//   Spill abort signature: VGPR pinned at a cap + WRITE >> 100MB.

#define TWO_N 128
#define OUT_N 10
#define LSTRIDE 758
// per-layer trig table layout (stride 758):
// [0,63) ct1 [63,126) st1 [126,189) cp1 [189,252) sp1
// [252,315) rot_c [315,378) rot_s [378,442) exp(-sq) [442,506) exp(+sq)
// [506,758) int2 trig (same sublayout as int1)

template<int S>
__device__ __forceinline__ void bs_apply(float (&col)[TWO_N], const float* t){
  #pragma unroll
  for (int i = S; i < 63; i += 2){
    float ct = t[i], st = t[63+i], cp = t[126+i], sp = t[189+i];
    float cs = cp*st, ss = sp*st;
    float a = col[i], b = col[i+1], e = col[64+i], f = col[65+i];
    col[i]    = ct*a - cs*b - ss*f;
    col[i+1]  = cs*a + ct*b - ss*e;
    col[64+i] = ss*b + ct*e - cs*f;
    col[65+i] = ss*a + cs*e + ct*f;
  }
}

__device__ __forceinline__ void rot_squeeze(float (&col)[TWO_N], const float* t){
  #pragma unroll
  for (int m = 0; m < 64; ++m){
    float cm = (m < 63) ? t[252+m] : 1.0f;
    float sm = (m < 63) ? t[315+m] : 0.0f;
    float em = t[378+m], ep = t[442+m];
    float u = col[m], v = col[64+m];
    col[m]    = em * (cm*u - sm*v);
    col[64+m] = ep * (sm*u + cm*v);
  }
}

__global__ __launch_bounds__(192, 1)
void cvqnn_setup(const float* __restrict__ i1_0, const float* __restrict__ sq_0,
                 const float* __restrict__ i2_0, const float* __restrict__ dp_0,
                 const float* __restrict__ i1_1, const float* __restrict__ sq_1,
                 const float* __restrict__ i2_1, const float* __restrict__ dp_1,
                 float* __restrict__ ws)
{
  __shared__ float trig[2*LSTRIDE];
  __shared__ float red[128*OUT_N];
  const int tid = threadIdx.x;

  // ---- parallel transcendental precompute ----
  for (int idx = tid; idx < 2*LSTRIDE; idx += 192){
    int L = idx / LSTRIDE, q = idx - L*LSTRIDE;
    const float* i1 = L ? i1_1 : i1_0;
    const float* i2 = L ? i2_1 : i2_0;
    const float* sq = L ? sq_1 : sq_0;
    float v;
    if (q < 252){
      int kind = q / 63, i = q - kind*63;
      float ang = (kind & 2) ? i1[3*i+1] : i1[3*i];
      v = (kind & 1) ? sinf(ang) : cosf(ang);
    } else if (q < 378){
      int kind = (q-252)/63, m = (q-252) - kind*63;
      float ang = i1[3*m+2];
      v = kind ? sinf(ang) : cosf(ang);
    } else if (q < 506){
      int kind = (q-378)/64, m = (q-378) - kind*64;
      v = expf(kind ? sq[m] : -sq[m]);
    } else {
      int qq = q - 506;
      int kind = qq / 63, i = qq - kind*63;
      float ang = (kind & 2) ? i2[3*i+1] : i2[3*i];
      v = (kind & 1) ? sinf(ang) : cosf(ang);
    }
    trig[idx] = v;
  }
  __syncthreads();

  // ---- column-local transform (no syncs needed: ops mix rows, not cols) ----
  float col[TWO_N];
  const int c = tid;
  if (c < 129){
    #pragma unroll
    for (int r = 0; r < TWO_N; ++r) col[r] = (r == c) ? 1.0f : 0.0f; // c==128 -> zeros (d)

    #pragma unroll
    for (int L = 0; L < 2; ++L){
      const float* tl = trig + L*LSTRIDE;
      bs_apply<0>(col, tl);
      bs_apply<1>(col, tl);
      rot_squeeze(col, tl);
      bs_apply<0>(col, tl + 506);
      bs_apply<1>(col, tl + 506);
      if (c == 128){
        const float* dp = L ? dp_1 : dp_0;
        #pragma unroll
        for (int m = 0; m < 64; ++m) col[m] += 2.0f * dp[m];
      }
    }

    // rows of interest: rr<10 -> row rr ; rr>=10 -> row 64+(rr-10) = 54+rr
    if (c < 64){
      #pragma unroll
      for (int rr = 0; rr < 20; ++rr){
        int row = (rr < 10) ? rr : (54 + rr);
        ws[c*20 + rr] = 2.0f * col[row];   // W[k=c][rr], factor 2 folded in
      }
    }
    if (c < 128){
      #pragma unroll
      for (int w = 0; w < OUT_N; ++w)
        red[c*OUT_N + w] = col[w]*col[w] + col[64+w]*col[64+w];
    }
    if (c == 128){
      #pragma unroll
      for (int rr = 0; rr < 20; ++rr){
        int row = (rr < 10) ? rr : (54 + rr);
        ws[1280 + rr] = col[row];          // bias = d[rows]
      }
    }
  }
  __syncthreads();
  if (tid < OUT_N){
    float s = 0.0f;
    for (int k = 0; k < 128; ++k) s += red[k*OUT_N + tid];
    ws[1300 + tid] = s;                    // cov_term[w]
  }
}

__device__ __forceinline__ void cvqnn_store(const float (&acc)[20], const float* shs,
                                            float* __restrict__ out, int b)
{
  float2* o = reinterpret_cast<float2*>(out + (size_t)b * 10); // 40B row, 8B aligned
  #pragma unroll
  for (int w = 0; w < OUT_N; w += 2){
    float mx0 = acc[w],   mp0 = acc[10+w];
    float nm0 = (shs[1300+w] + mx0*mx0 + mp0*mp0) * 0.25f - 0.5f;
    float r0  = log1pf(fmaxf(nm0, 0.0f));
    float mx1 = acc[w+1], mp1 = acc[11+w];
    float nm1 = (shs[1301+w] + mx1*mx1 + mp1*mp1) * 0.25f - 0.5f;
    float r1  = log1pf(fmaxf(nm1, 0.0f));
    o[w >> 1] = make_float2(r0, r1);
  }
}

__global__
void cvqnn_main(const float* __restrict__ x, const float* __restrict__ ws,
                float* __restrict__ out, int B)
{
  // shs: [0,1280) W (layout k*20+rr), [1280,1300) bias, [1300,1310) cterm
  __shared__ __align__(16) float shs[1310];
  const int tid = threadIdx.x;
  #pragma unroll
  for (int i = 0; i < 6; ++i){
    int idx = i*256 + tid;
    if (idx < 1310) shs[idx] = ws[idx];
  }
  __syncthreads();

  const int base = blockIdx.x * 512;
  const int b0 = base + tid;
  const int b1 = base + 256 + tid;
  const bool v0 = b0 < B, v1 = b1 < B;
  const int rb0 = v0 ? b0 : 0;            // clamp OOB rows: load row 0, never store
  const int rb1 = v1 ? b1 : 0;

  const float4* x40 = reinterpret_cast<const float4*>(x) + ((size_t)rb0 << 4);
  const float4* x41 = reinterpret_cast<const float4*>(x) + ((size_t)rb1 << 4);

  float acc0[20], acc1[20];
  #pragma unroll
  for (int r = 0; r < 20; ++r){ float bv = shs[1280 + r]; acc0[r] = bv; acc1[r] = bv; }

  #pragma unroll 1   // keep halves separate (no cross-phase load hoisting)
  for (int half = 0; half < 2; ++half){
    // one full 128B cache line per row, 8+8 back-to-back dwordx4 -> 16-deep MLP
    float4 xr0[8], xr1[8];
    #pragma unroll
    for (int i = 0; i < 8; ++i) xr0[i] = x40[(half << 3) + i];
    #pragma unroll
    for (int i = 0; i < 8; ++i) xr1[i] = x41[(half << 3) + i];

    const float* wh = shs + half*640;
    #pragma unroll
    for (int k4 = 0; k4 < 8; ++k4){
      float4 cx0 = xr0[k4], cx1 = xr1[k4];  // compile-time index -> stays in regs
      const float* wb = wh + k4*80;         // uniform LDS address -> broadcast
      #pragma unroll
      for (int q = 0; q < 4; ++q){
        float xs0 = (q == 0) ? cx0.x : (q == 1) ? cx0.y : (q == 2) ? cx0.z : cx0.w;
        float xs1 = (q == 0) ? cx1.x : (q == 1) ? cx1.y : (q == 2) ? cx1.z : cx1.w;
        const float4* wv = reinterpret_cast<const float4*>(wb + q*20);
        #pragma unroll
        for (int m = 0; m < 5; ++m){
          float4 w = wv[m];               // ONE W read feeds BOTH rows (8 FMAs)
          acc0[4*m+0] = fmaf(xs0, w.x, acc0[4*m+0]);
          acc0[4*m+1] = fmaf(xs0, w.y, acc0[4*m+1]);
          acc0[4*m+2] = fmaf(xs0, w.z, acc0[4*m+2]);
          acc0[4*m+3] = fmaf(xs0, w.w, acc0[4*m+3]);
          acc1[4*m+0] = fmaf(xs1, w.x, acc1[4*m+0]);
          acc1[4*m+1] = fmaf(xs1, w.y, acc1[4*m+1]);
          acc1[4*m+2] = fmaf(xs1, w.z, acc1[4*m+2]);
          acc1[4*m+3] = fmaf(xs1, w.w, acc1[4*m+3]);
        }
      }
    }
  }

  if (v0) cvqnn_store(acc0, shs, out, b0);
  if (v1) cvqnn_store(acc1, shs, out, b1);
}

extern "C" void kernel_launch(void* const* d_in, const int* in_sizes, int n_in,
                              void* d_out, int out_size, void* d_ws, size_t ws_size,
                              hipStream_t stream)
{
  const float* x    = (const float*)d_in[0];
  const float* i1_0 = (const float*)d_in[1];
  const float* sq_0 = (const float*)d_in[2];
  const float* i2_0 = (const float*)d_in[3];
  const float* dp_0 = (const float*)d_in[4];
  const float* i1_1 = (const float*)d_in[5];
  const float* sq_1 = (const float*)d_in[6];
  const float* i2_1 = (const float*)d_in[7];
  const float* dp_1 = (const float*)d_in[8];
  float* ws = (float*)d_ws;

  int B = in_sizes[0] / 64;

  cvqnn_setup<<<1, 192, 0, stream>>>(i1_0, sq_0, i2_0, dp_0,
                                     i1_1, sq_1, i2_1, dp_1, ws);

  int grid = (B + 511) / 512;   // 512 rows per block (2 per thread), balanced
  cvqnn_main<<<grid, 256, 0, stream>>>(x, ws, (float*)d_out, B);
}

// Round 8
// 499.949 us; speedup vs baseline: 4.0152x; 4.0152x over previous
//
#include <hip/hip_runtime.h>
#include <hip/hip_bf16.h>
#include <math.h>

// CVQNN classifier, N=64 modes, OUT=10, HBAR=2.
// Kernel 1 (1 block, 192 thr): build S (128x128 symplectic, 2 layers) and d.
//   Thread c holds column c of S in registers (ops are column-local).
//   Thread 128 carries the displacement vector d through the same ops.
//   Emits to ws: W[k][rr] = 2*S[rows[rr],k] (k<64, 1280 fl),
//                bias[rr] = d[rows[rr]] (20 fl), cterm[w] (10 fl).
// Kernel 2: W/bias/cterm in LDS (uniform-address broadcast reads).
//   Model (rounds 3/5/6): duration ~= per-CU LDS-read-pipe time; the pipe
//   saturates at ~8 resident waves/CU, so occupancy is not the lever --
//   per-thread LDS volume is. TWO rows per thread share every W read
//   (total b128 halves to 2.5M), full-128B-line bursts keep FETCH
//   compulsory-only + 16-deep MLP (round-4 lesson).
//   LAUNCH-BOUNDS MAP (hard-won, rounds 2/4/6/7): none => 64-reg cap
//   (compiler default, SPILLS); (256,4) => 64 cap (SPILLS); (256,2) =>
//   128 cap (this structure SPILLS at ~150 live); bare (256) => uncapped,
//   round 1 ran 196 VGPR with ZERO spill. This round: bare (256), nothing
//   else changed vs round 6/7. Spill signature = VGPR pinned at 64/128 +
//   WRITE >> 100MB.

#define TWO_N 128
#define OUT_N 10
#define LSTRIDE 758
// per-layer trig table layout (stride 758):
// [0,63) ct1 [63,126) st1 [126,189) cp1 [189,252) sp1
// [252,315) rot_c [315,378) rot_s [378,442) exp(-sq) [442,506) exp(+sq)
// [506,758) int2 trig (same sublayout as int1)

template<int S>
__device__ __forceinline__ void bs_apply(float (&col)[TWO_N], const float* t){
  #pragma unroll
  for (int i = S; i < 63; i += 2){
    float ct = t[i], st = t[63+i], cp = t[126+i], sp = t[189+i];
    float cs = cp*st, ss = sp*st;
    float a = col[i], b = col[i+1], e = col[64+i], f = col[65+i];
    col[i]    = ct*a - cs*b - ss*f;
    col[i+1]  = cs*a + ct*b - ss*e;
    col[64+i] = ss*b + ct*e - cs*f;
    col[65+i] = ss*a + cs*e + ct*f;
  }
}

__device__ __forceinline__ void rot_squeeze(float (&col)[TWO_N], const float* t){
  #pragma unroll
  for (int m = 0; m < 64; ++m){
    float cm = (m < 63) ? t[252+m] : 1.0f;
    float sm = (m < 63) ? t[315+m] : 0.0f;
    float em = t[378+m], ep = t[442+m];
    float u = col[m], v = col[64+m];
    col[m]    = em * (cm*u - sm*v);
    col[64+m] = ep * (sm*u + cm*v);
  }
}

__global__ __launch_bounds__(192, 1)
void cvqnn_setup(const float* __restrict__ i1_0, const float* __restrict__ sq_0,
                 const float* __restrict__ i2_0, const float* __restrict__ dp_0,
                 const float* __restrict__ i1_1, const float* __restrict__ sq_1,
                 const float* __restrict__ i2_1, const float* __restrict__ dp_1,
                 float* __restrict__ ws)
{
  __shared__ float trig[2*LSTRIDE];
  __shared__ float red[128*OUT_N];
  const int tid = threadIdx.x;

  // ---- parallel transcendental precompute ----
  for (int idx = tid; idx < 2*LSTRIDE; idx += 192){
    int L = idx / LSTRIDE, q = idx - L*LSTRIDE;
    const float* i1 = L ? i1_1 : i1_0;
    const float* i2 = L ? i2_1 : i2_0;
    const float* sq = L ? sq_1 : sq_0;
    float v;
    if (q < 252){
      int kind = q / 63, i = q - kind*63;
      float ang = (kind & 2) ? i1[3*i+1] : i1[3*i];
      v = (kind & 1) ? sinf(ang) : cosf(ang);
    } else if (q < 378){
      int kind = (q-252)/63, m = (q-252) - kind*63;
      float ang = i1[3*m+2];
      v = kind ? sinf(ang) : cosf(ang);
    } else if (q < 506){
      int kind = (q-378)/64, m = (q-378) - kind*64;
      v = expf(kind ? sq[m] : -sq[m]);
    } else {
      int qq = q - 506;
      int kind = qq / 63, i = qq - kind*63;
      float ang = (kind & 2) ? i2[3*i+1] : i2[3*i];
      v = (kind & 1) ? sinf(ang) : cosf(ang);
    }
    trig[idx] = v;
  }
  __syncthreads();

  // ---- column-local transform (no syncs needed: ops mix rows, not cols) ----
  float col[TWO_N];
  const int c = tid;
  if (c < 129){
    #pragma unroll
    for (int r = 0; r < TWO_N; ++r) col[r] = (r == c) ? 1.0f : 0.0f; // c==128 -> zeros (d)

    #pragma unroll
    for (int L = 0; L < 2; ++L){
      const float* tl = trig + L*LSTRIDE;
      bs_apply<0>(col, tl);
      bs_apply<1>(col, tl);
      rot_squeeze(col, tl);
      bs_apply<0>(col, tl + 506);
      bs_apply<1>(col, tl + 506);
      if (c == 128){
        const float* dp = L ? dp_1 : dp_0;
        #pragma unroll
        for (int m = 0; m < 64; ++m) col[m] += 2.0f * dp[m];
      }
    }

    // rows of interest: rr<10 -> row rr ; rr>=10 -> row 64+(rr-10) = 54+rr
    if (c < 64){
      #pragma unroll
      for (int rr = 0; rr < 20; ++rr){
        int row = (rr < 10) ? rr : (54 + rr);
        ws[c*20 + rr] = 2.0f * col[row];   // W[k=c][rr], factor 2 folded in
      }
    }
    if (c < 128){
      #pragma unroll
      for (int w = 0; w < OUT_N; ++w)
        red[c*OUT_N + w] = col[w]*col[w] + col[64+w]*col[64+w];
    }
    if (c == 128){
      #pragma unroll
      for (int rr = 0; rr < 20; ++rr){
        int row = (rr < 10) ? rr : (54 + rr);
        ws[1280 + rr] = col[row];          // bias = d[rows]
      }
    }
  }
  __syncthreads();
  if (tid < OUT_N){
    float s = 0.0f;
    for (int k = 0; k < 128; ++k) s += red[k*OUT_N + tid];
    ws[1300 + tid] = s;                    // cov_term[w]
  }
}

__device__ __forceinline__ void cvqnn_store(const float (&acc)[20], const float* shs,
                                            float* __restrict__ out, int b)
{
  float2* o = reinterpret_cast<float2*>(out + (size_t)b * 10); // 40B row, 8B aligned
  #pragma unroll
  for (int w = 0; w < OUT_N; w += 2){
    float mx0 = acc[w],   mp0 = acc[10+w];
    float nm0 = (shs[1300+w] + mx0*mx0 + mp0*mp0) * 0.25f - 0.5f;
    float r0  = log1pf(fmaxf(nm0, 0.0f));
    float mx1 = acc[w+1], mp1 = acc[11+w];
    float nm1 = (shs[1301+w] + mx1*mx1 + mp1*mp1) * 0.25f - 0.5f;
    float r1  = log1pf(fmaxf(nm1, 0.0f));
    o[w >> 1] = make_float2(r0, r1);
  }
}

__global__ __launch_bounds__(256)
void cvqnn_main(const float* __restrict__ x, const float* __restrict__ ws,
                float* __restrict__ out, int B)
{
  // shs: [0,1280) W (layout k*20+rr), [1280,1300) bias, [1300,1310) cterm
  __shared__ __align__(16) float shs[1310];
  const int tid = threadIdx.x;
  #pragma unroll
  for (int i = 0; i < 6; ++i){
    int idx = i*256 + tid;
    if (idx < 1310) shs[idx] = ws[idx];
  }
  __syncthreads();

  const int base = blockIdx.x * 512;
  const int b0 = base + tid;
  const int b1 = base + 256 + tid;
  const bool v0 = b0 < B, v1 = b1 < B;
  const int rb0 = v0 ? b0 : 0;            // clamp OOB rows: load row 0, never store
  const int rb1 = v1 ? b1 : 0;

  const float4* x40 = reinterpret_cast<const float4*>(x) + ((size_t)rb0 << 4);
  const float4* x41 = reinterpret_cast<const float4*>(x) + ((size_t)rb1 << 4);

  float acc0[20], acc1[20];
  #pragma unroll
  for (int r = 0; r < 20; ++r){ float bv = shs[1280 + r]; acc0[r] = bv; acc1[r] = bv; }

  #pragma unroll 1   // keep halves separate (no cross-phase load hoisting)
  for (int half = 0; half < 2; ++half){
    // one full 128B cache line per row, 8+8 back-to-back dwordx4 -> 16-deep MLP
    float4 xr0[8], xr1[8];
    #pragma unroll
    for (int i = 0; i < 8; ++i) xr0[i] = x40[(half << 3) + i];
    #pragma unroll
    for (int i = 0; i < 8; ++i) xr1[i] = x41[(half << 3) + i];

    const float* wh = shs + half*640;
    #pragma unroll
    for (int k4 = 0; k4 < 8; ++k4){
      float4 cx0 = xr0[k4], cx1 = xr1[k4];  // compile-time index -> stays in regs
      const float* wb = wh + k4*80;         // uniform LDS address -> broadcast
      #pragma unroll
      for (int q = 0; q < 4; ++q){
        float xs0 = (q == 0) ? cx0.x : (q == 1) ? cx0.y : (q == 2) ? cx0.z : cx0.w;
        float xs1 = (q == 0) ? cx1.x : (q == 1) ? cx1.y : (q == 2) ? cx1.z : cx1.w;
        const float4* wv = reinterpret_cast<const float4*>(wb + q*20);
        #pragma unroll
        for (int m = 0; m < 5; ++m){
          float4 w = wv[m];               // ONE W read feeds BOTH rows (8 FMAs)
          acc0[4*m+0] = fmaf(xs0, w.x, acc0[4*m+0]);
          acc0[4*m+1] = fmaf(xs0, w.y, acc0[4*m+1]);
          acc0[4*m+2] = fmaf(xs0, w.z, acc0[4*m+2]);
          acc0[4*m+3] = fmaf(xs0, w.w, acc0[4*m+3]);
          acc1[4*m+0] = fmaf(xs1, w.x, acc1[4*m+0]);
          acc1[4*m+1] = fmaf(xs1, w.y, acc1[4*m+1]);
          acc1[4*m+2] = fmaf(xs1, w.z, acc1[4*m+2]);
          acc1[4*m+3] = fmaf(xs1, w.w, acc1[4*m+3]);
        }
      }
    }
  }

  if (v0) cvqnn_store(acc0, shs, out, b0);
  if (v1) cvqnn_store(acc1, shs, out, b1);
}

extern "C" void kernel_launch(void* const* d_in, const int* in_sizes, int n_in,
                              void* d_out, int out_size, void* d_ws, size_t ws_size,
                              hipStream_t stream)
{
  const float* x    = (const float*)d_in[0];
  const float* i1_0 = (const float*)d_in[1];
  const float* sq_0 = (const float*)d_in[2];
  const float* i2_0 = (const float*)d_in[3];
  const float* dp_0 = (const float*)d_in[4];
  const float* i1_1 = (const float*)d_in[5];
  const float* sq_1 = (const float*)d_in[6];
  const float* i2_1 = (const float*)d_in[7];
  const float* dp_1 = (const float*)d_in[8];
  float* ws = (float*)d_ws;

  int B = in_sizes[0] / 64;

  cvqnn_setup<<<1, 192, 0, stream>>>(i1_0, sq_0, i2_0, dp_0,
                                     i1_1, sq_1, i2_1, dp_1, ws);

  int grid = (B + 511) / 512;   // 512 rows per block (2 per thread), balanced
  cvqnn_main<<<grid, 256, 0, stream>>>(x, ws, (float*)d_out, B);
}